// Round 12
// baseline (18.564 us; speedup 1.0000x reference)
//
#include <hip/hip_runtime.h>

// LocalLinearLayer, SINGLE dispatch: banded bf16 MFMA (R9 structure).
// out[b,o,c] = bias[o] + sum_{j=0..24} W[o, o+j] * xp[b, o+j, c]
// xp[q] = x[q] (q<12), x[q-12] (12<=q<4108), x[q-24] (q>=4108)
//
// Per 16-output tile at o0, kappa in [0,64):
//   out[o0+m'][c] = sum_kappa A[m'][kappa] * B[kappa][c]
//   A[m'][kappa] = W[o0+m', kappa-m'] (0<=kappa-m'<25 else 0)
//   B[kappa][c]  = xp[o0+kappa][c]
// R12 = R9 + (x HBM loads issued before W L2 loads) + nontemporal out stores
// (out is write-once; keep it from evicting the L2-resident W band + x halo).

typedef __attribute__((ext_vector_type(8))) short short8;
typedef __attribute__((ext_vector_type(4))) float f32x4;

constexpr int Lseq = 4096;
constexpr int C    = 64;
constexpr int WIN  = 25;
constexpr int PAD  = 12;
constexpr int O_B  = 128;          // outputs per block (4 waves x 2 tiles x 16)
constexpr int PWIN = 176;          // taps staged (128 + 48 halo)
constexpr int PLX  = 184;          // x_lds row stride (shorts); non-pow2 bank spread
constexpr int WROW = 28;           // w_band row stride (floats)
constexpr int NB   = 32;

__device__ __forceinline__ ushort f2bf(float f) {
    union { float f; uint u; } v; v.f = f;
    uint r = v.u + 0x7FFFu + ((v.u >> 16) & 1u);   // round-to-nearest-even
    return (ushort)(r >> 16);
}

__device__ __forceinline__ int tap_to_t(int q) {
    int t = (q < PAD) ? q : ((q < Lseq + PAD) ? q - PAD : q - 2 * PAD);
    return t > Lseq - 1 ? Lseq - 1 : t;   // clamped taps always meet zero weights
}

__global__ __launch_bounds__(256) void lll_one(const float* __restrict__ x,
                                               const float* __restrict__ W,
                                               const float* __restrict__ bias,
                                               float* __restrict__ out) {
    __shared__ ushort x_lds[C * PLX];        // 23.0 KB: x bf16, [channel][tap]
    __shared__ float  w_band[O_B * WROW];    // 14.3 KB: raw band rows, f32

    const int bid   = blockIdx.x;
    const int tile  = bid >> 5;              // tile-major: bid+-32 = halo neighbor
    const int b     = bid & 31;
    const int blk_o = tile * O_B;

    const int tid  = threadIdx.x;
    const int lane = tid & 63;
    const int w    = tid >> 6;
    const int m    = lane & 15;
    const int quad = lane >> 4;

    // ---- issue x global loads FIRST (HBM-critical stream) ----
    const float4* xb = (const float4*)(x + (size_t)b * Lseq * C);
    float4 f[2][8];
    const bool has2 = tid < 16 * (PWIN / 8) - 256;   // 352 units total
#pragma unroll
    for (int s = 0; s < 2; ++s) {
        if (s == 1 && !has2) break;
        const int u = tid + 256 * s;
        const int c4 = u & 15, oct = u >> 4, p0 = oct * 8;
#pragma unroll
        for (int i = 0; i < 8; ++i)
            f[s][i] = xb[(size_t)tap_to_t(blk_o + p0 + i) * 16 + c4];
    }

    // ---- stage W band rows -> LDS, f32, per-row coalesced (L2-hit mostly) ----
    {
        const int row = tid >> 1, h = tid & 1;
        const float* wr = W + (size_t)(blk_o + row) * 4121 + h * 12;
        float v[13];
#pragma unroll
        for (int i = 0; i < 13; ++i) v[i] = wr[i];
        float* dst = &w_band[row * WROW + h * 12];
#pragma unroll
        for (int i = 0; i < 13; ++i) dst[i] = v[i];
    }

    // ---- pack x -> bf16, b128 LDS writes ----
#pragma unroll
    for (int s = 0; s < 2; ++s) {
        if (s == 1 && !has2) break;
        const int u = tid + 256 * s;
        const int c4 = u & 15, oct = u >> 4, p0 = oct * 8;
#pragma unroll
        for (int ch = 0; ch < 4; ++ch) {
            short8 pk;
#pragma unroll
            for (int i = 0; i < 8; ++i) {
                const float v = (ch == 0) ? f[s][i].x : (ch == 1) ? f[s][i].y
                              : (ch == 2) ? f[s][i].z : f[s][i].w;
                pk[i] = (short)f2bf(v);
            }
            *(short8*)&x_lds[(c4 * 4 + ch) * PLX + p0] = pk;
        }
    }
    __syncthreads();

    // ---- gather A-fragments from w_band (LDS), pack bf16 in registers ----
    short8 afrag[2][2];
#pragma unroll
    for (int it = 0; it < 2; ++it) {
        const int row = (w * 2 + it) * 16 + m;            // relative band row
#pragma unroll
        for (int cch = 0; cch < 2; ++cch) {
            const int j0 = cch * 32 + quad * 8 - m;
            short8 pk;
#pragma unroll
            for (int e = 0; e < 8; ++e) {
                const int j  = j0 + e;
                const int jc = min(max(j, 0), WIN - 1);
                const float g = w_band[row * WROW + jc];
                pk[e] = (short)f2bf((j == jc) ? g : 0.f);
            }
            afrag[it][cch] = pk;
        }
    }

    // ---- compute: 2 tiles/wave; nontemporal scalar stores ----
    float* ob = out + (size_t)b * Lseq * C;
#pragma unroll
    for (int it = 0; it < 2; ++it) {
        const int t16 = w * 2 + it;
        const int o0  = blk_o + t16 * 16;

        f32x4 acc[4];
        {
            const float4 bv = *((const float4*)(bias + o0) + quad);
            const float bb[4] = {bv.x, bv.y, bv.z, bv.w};
#pragma unroll
            for (int r = 0; r < 4; ++r)
#pragma unroll
                for (int g = 0; g < 4; ++g) acc[g][r] = bb[r];
        }

#pragma unroll
        for (int cch = 0; cch < 2; ++cch) {
            const int poff = t16 * 16 + cch * 32 + quad * 8;
#pragma unroll
            for (int g = 0; g < 4; ++g) {
                short8 bf = *(const short8*)&x_lds[(m + 16 * g) * PLX + poff];
                acc[g] = __builtin_amdgcn_mfma_f32_16x16x32_bf16(afrag[it][cch], bf,
                                                                 acc[g], 0, 0, 0);
            }
        }

#pragma unroll
        for (int g = 0; g < 4; ++g)
#pragma unroll
            for (int r = 0; r < 4; ++r)
                __builtin_nontemporal_store(
                    acc[g][r], ob + (size_t)(o0 + quad * 4 + r) * C + m + 16 * g);
    }
}

extern "C" void kernel_launch(void* const* d_in, const int* in_sizes, int n_in,
                              void* d_out, int out_size, void* d_ws, size_t ws_size,
                              hipStream_t stream) {
    const float* x    = (const float*)d_in[0];
    const float* W    = (const float*)d_in[1];
    const float* bias = (const float*)d_in[2];
    float*       out  = (float*)d_out;

    lll_one<<<NB * (Lseq / O_B), 256, 0, stream>>>(x, W, bias, out);  // 1024 blocks
}